// Round 1
// baseline (2614.547 us; speedup 1.0000x reference)
//
#include <hip/hip_runtime.h>
#include <math.h>

// Problem constants (from reference)
constexpr int Bsz  = 8;
constexpr int Ntok = 1920;
constexpr int Cdim = 512;
constexpr int BLK  = 192;
constexpr int Mrows = Bsz * Ntok;      // 15360
constexpr int NBLK  = Mrows / BLK;     // 80
constexpr float SCALE = 0.02209708691207961f;  // 2048^-0.5

// ---------------- token mean (two-stage, no atomics) ----------------
__global__ void mean_partial(const float* __restrict__ g, float* __restrict__ part) {
    int b = blockIdx.x, t = blockIdx.y, c = threadIdx.x;   // 512 threads
    const float* p = g + ((size_t)b * Ntok + (size_t)t * 48) * Cdim + c;
    float s = 0.f;
    #pragma unroll 4
    for (int n = 0; n < 48; ++n) s += p[(size_t)n * Cdim];
    part[((size_t)b * 40 + t) * Cdim + c] = s;
}

__global__ void mean_final(const float* __restrict__ part, float* __restrict__ meang) {
    int b = blockIdx.x, c = threadIdx.x;                   // 512 threads
    float s = 0.f;
    for (int t = 0; t < 40; ++t) s += part[((size_t)b * 40 + t) * Cdim + c];
    meang[b * Cdim + c] = s * (1.0f / (float)Ntok);
}

// ---------------- per-row inverse norm of g ----------------
__global__ void invnorm_k(const float* __restrict__ g, float* __restrict__ invn) {
    int wid = threadIdx.x >> 6, lane = threadIdx.x & 63;
    int row = blockIdx.x * 4 + wid;                        // 4 waves/block
    const float* p = g + (size_t)row * Cdim;
    float ss = 0.f;
    #pragma unroll
    for (int i = lane; i < Cdim; i += 64) { float v = p[i]; ss += v * v; }
    #pragma unroll
    for (int o = 1; o < 64; o <<= 1) ss += __shfl_xor(ss, o);
    if (lane == 0) {
        float n = sqrtf(ss);
        invn[row] = 1.0f / fmaxf(n, 1e-12f);
    }
}

// ---------------- generic tiled GEMM: O = alpha * rs*cs * (A · B^T) ----------------
// A[M,K] row-major, B[N,K] row-major, O[M,N]. Optional per-row A bias (meang),
// optional row/col output scales (invn), batched over blockIdx.z.
__global__ __launch_bounds__(256) void gemm_nt(
    const float* __restrict__ A, const float* __restrict__ Bm, float* __restrict__ O,
    int M, int Nn, int K,
    long aBatch, long bBatch, long oBatch,
    float alpha, const float* __restrict__ rs, const float* __restrict__ cs, int sBatch,
    const float* __restrict__ abias)
{
    int z = blockIdx.z;
    A  += (size_t)z * aBatch;
    Bm += (size_t)z * bBatch;
    O  += (size_t)z * oBatch;
    int n0 = blockIdx.x * 64, m0 = blockIdx.y * 64;

    __shared__ float As[16][65];
    __shared__ float Bs[16][65];

    int tid = threadIdx.x;
    int tx = tid & 15, ty = tid >> 4;
    int lk = tid & 15;            // k within tile
    int lr = (tid >> 4) * 4;      // row base (4 rows per thread)
    float acc[4][4] = {};

    for (int k0 = 0; k0 < K; k0 += 16) {
        #pragma unroll
        for (int r = 0; r < 4; ++r) {
            int gm = m0 + lr + r;
            float v = A[(size_t)gm * K + k0 + lk];
            if (abias) v += abias[(gm / Ntok) * Cdim + k0 + lk];
            As[lk][lr + r] = v;
        }
        #pragma unroll
        for (int r = 0; r < 4; ++r) {
            int gn = n0 + lr + r;
            Bs[lk][lr + r] = Bm[(size_t)gn * K + k0 + lk];
        }
        __syncthreads();
        #pragma unroll
        for (int kk = 0; kk < 16; ++kk) {
            float a[4], bv[4];
            #pragma unroll
            for (int i = 0; i < 4; ++i) a[i] = As[kk][ty * 4 + i];
            #pragma unroll
            for (int j = 0; j < 4; ++j) bv[j] = Bs[kk][tx * 4 + j];
            #pragma unroll
            for (int i = 0; i < 4; ++i)
                #pragma unroll
                for (int j = 0; j < 4; ++j) acc[i][j] += a[i] * bv[j];
        }
        __syncthreads();
    }

    #pragma unroll
    for (int i = 0; i < 4; ++i) {
        int gm = m0 + ty * 4 + i;
        float rfac = alpha * (rs ? rs[(size_t)z * sBatch + gm] : 1.0f);
        #pragma unroll
        for (int j = 0; j < 4; ++j) {
            int gn = n0 + tx * 4 + j;
            float fac = rfac * (cs ? cs[(size_t)z * sBatch + gn] : 1.0f);
            O[(size_t)gm * Nn + gn] = acc[i][j] * fac;
        }
    }
}

// ---------------- generic tiled GEMM: O = A · B ----------------
// A[M,K] row-major, B[K,N] row-major, O[M,N]. Batched over blockIdx.z.
__global__ __launch_bounds__(256) void gemm_nn(
    const float* __restrict__ A, const float* __restrict__ Bm, float* __restrict__ O,
    int M, int Nn, int K,
    long aBatch, long bBatch, long oBatch)
{
    int z = blockIdx.z;
    A  += (size_t)z * aBatch;
    Bm += (size_t)z * bBatch;
    O  += (size_t)z * oBatch;
    int n0 = blockIdx.x * 64, m0 = blockIdx.y * 64;

    __shared__ float As[16][65];
    __shared__ float Bs[16][65];

    int tid = threadIdx.x;
    int tx = tid & 15, ty = tid >> 4;
    int lk = tid & 15;
    int lr = (tid >> 4) * 4;
    int bn = tid & 63;            // col for B loads (coalesced)
    int bk4 = (tid >> 6) * 4;     // k base for B loads
    float acc[4][4] = {};

    for (int k0 = 0; k0 < K; k0 += 16) {
        #pragma unroll
        for (int r = 0; r < 4; ++r) {
            int gm = m0 + lr + r;
            As[lk][lr + r] = A[(size_t)gm * K + k0 + lk];
        }
        #pragma unroll
        for (int r = 0; r < 4; ++r) {
            int kk = bk4 + r;
            Bs[kk][bn] = Bm[(size_t)(k0 + kk) * Nn + n0 + bn];
        }
        __syncthreads();
        #pragma unroll
        for (int kk = 0; kk < 16; ++kk) {
            float a[4], bv[4];
            #pragma unroll
            for (int i = 0; i < 4; ++i) a[i] = As[kk][ty * 4 + i];
            #pragma unroll
            for (int j = 0; j < 4; ++j) bv[j] = Bs[kk][tx * 4 + j];
            #pragma unroll
            for (int i = 0; i < 4; ++i)
                #pragma unroll
                for (int j = 0; j < 4; ++j) acc[i][j] += a[i] * bv[j];
        }
        __syncthreads();
    }

    #pragma unroll
    for (int i = 0; i < 4; ++i) {
        int gm = m0 + ty * 4 + i;
        #pragma unroll
        for (int j = 0; j < 4; ++j) {
            int gn = n0 + tx * 4 + j;
            O[(size_t)gm * Nn + gn] = acc[i][j];
        }
    }
}

// ---------------- row softmax (row cached in LDS) ----------------
__global__ __launch_bounds__(256) void softmax_rows(float* __restrict__ S, int cols) {
    __shared__ float buf[1920];
    __shared__ float red[8];
    size_t row = blockIdx.x;
    float* p = S + row * (size_t)cols;
    int tid = threadIdx.x;

    float lmax = -1e30f;
    for (int c = tid; c < cols; c += 256) { float v = p[c]; buf[c] = v; lmax = fmaxf(lmax, v); }
    #pragma unroll
    for (int o = 1; o < 64; o <<= 1) lmax = fmaxf(lmax, __shfl_xor(lmax, o));
    if ((tid & 63) == 0) red[tid >> 6] = lmax;
    __syncthreads();
    float bmax = fmaxf(fmaxf(red[0], red[1]), fmaxf(red[2], red[3]));

    float lsum = 0.f;
    for (int c = tid; c < cols; c += 256) { float e = expf(buf[c] - bmax); buf[c] = e; lsum += e; }
    #pragma unroll
    for (int o = 1; o < 64; o <<= 1) lsum += __shfl_xor(lsum, o);
    __syncthreads();
    if ((tid & 63) == 0) red[tid >> 6] = lsum;
    __syncthreads();
    float inv = 1.0f / (red[0] + red[1] + red[2] + red[3]);
    for (int c = tid; c < cols; c += 256) p[c] = buf[c] * inv;
}

// ---------------- launch ----------------
extern "C" void kernel_launch(void* const* d_in, const int* in_sizes, int n_in,
                              void* d_out, int out_size, void* d_ws, size_t ws_size,
                              hipStream_t stream) {
    (void)in_sizes; (void)n_in; (void)out_size; (void)ws_size;
    const float* x  = (const float*)d_in[0];
    const float* g  = (const float*)d_in[1];
    const float* Wq = (const float*)d_in[2];
    const float* Wg = (const float*)d_in[3];
    float* out = (float*)d_out;

    char* ws = (char*)d_ws;
    // ws layout (bytes)
    float* meang = (float*)(ws);                                  // 8*512*4        = 16 KB
    float* part  = (float*)(ws + (16u << 10));                    // 8*40*512*4     = 640 KB
    float* invn  = (float*)(ws + (16u << 10) + 655360u);          // 15360*4        = 60 KB
    size_t o0 = (16u << 10) + 655360u + 61440u;                   // 733184
    float* relq = (float*)(ws + o0);                              // 15360*512*4    = 31.46 MB
    float* g2   = (float*)(ws + o0 + 31457280u);
    float* relg = (float*)(ws + o0 + 2u * 31457280u);
    float* sc   = (float*)(ws + o0 + 3u * 31457280u);             // max(80*192*192, 1920*1920)*4 = 14.75 MB

    // 1. token mean of g
    mean_partial<<<dim3(Bsz, 40), 512, 0, stream>>>(g, part);
    mean_final<<<Bsz, 512, 0, stream>>>(part, meang);

    // 2. per-row inv norms of g
    invnorm_k<<<Mrows / 4, 256, 0, stream>>>(g, invn);

    // 3. rel_q = (x + meang) @ Wq^T   [15360, 512]
    gemm_nt<<<dim3(Cdim / 64, Mrows / 64), 256, 0, stream>>>(
        x, Wq, relq, Mrows, Cdim, Cdim, 0, 0, 0, 1.0f, nullptr, nullptr, 0, meang);

    // 4. block scores: sc[z][i][j] = (g_i . g_j) * invn_i * invn_j * SCALE, z = 0..79
    gemm_nt<<<dim3(BLK / 64, BLK / 64, NBLK), 256, 0, stream>>>(
        g, g, sc, BLK, BLK, Cdim,
        (long)BLK * Cdim, (long)BLK * Cdim, (long)BLK * BLK,
        SCALE, invn, invn, BLK, nullptr);

    // 5. block softmax (80*192 rows of 192)
    softmax_rows<<<NBLK * BLK, 256, 0, stream>>>(sc, BLK);

    // 6. g2[z] = attn[z] @ gb[z]   [192, 512] per block
    gemm_nn<<<dim3(Cdim / 64, BLK / 64, NBLK), 256, 0, stream>>>(
        sc, g, g2, BLK, Cdim, BLK,
        (long)BLK * BLK, (long)BLK * Cdim, (long)BLK * Cdim);

    // 7. rel_g = g2 @ Wg^T   [15360, 512]
    gemm_nt<<<dim3(Cdim / 64, Mrows / 64), 256, 0, stream>>>(
        g2, Wg, relg, Mrows, Cdim, Cdim, 0, 0, 0, 1.0f, nullptr, nullptr, 0, nullptr);

    // 8. per-batch global attention (scores scratch reused sequentially)
    for (int b = 0; b < Bsz; ++b) {
        size_t off = (size_t)b * Ntok * Cdim;
        // scores2 = rel_q[b] @ rel_g[b]^T * SCALE   [1920, 1920]
        gemm_nt<<<dim3(Ntok / 64, Ntok / 64), 256, 0, stream>>>(
            relq + off, relg + off, sc, Ntok, Ntok, Cdim,
            0, 0, 0, SCALE, nullptr, nullptr, 0, nullptr);
        // softmax rows
        softmax_rows<<<Ntok, 256, 0, stream>>>(sc, Ntok);
        // out[b] = attn2 @ g2[b]   [1920, 512]
        gemm_nn<<<dim3(Cdim / 64, Ntok / 64), 256, 0, stream>>>(
            sc, g2 + off, out + off, Ntok, Cdim, Ntok, 0, 0, 0);
    }
}

// Round 2
// 1341.496 us; speedup vs baseline: 1.9490x; 1.9490x over previous
//
#include <hip/hip_runtime.h>
#include <math.h>

// Problem constants
constexpr int Bsz  = 8;
constexpr int Ntok = 1920;
constexpr int Cdim = 512;
constexpr int BLK  = 192;
constexpr int Mrows = Bsz * Ntok;      // 15360
constexpr int NBLK  = Mrows / BLK;     // 80
constexpr float SCALE = 0.02209708691207961f;  // 2048^-0.5

typedef __bf16 bf16x8 __attribute__((ext_vector_type(8)));
typedef float  f32x4  __attribute__((ext_vector_type(4)));

// ---- bf16 helpers (RNE, finite values only) ----
__device__ inline unsigned short f2bf(float f) {
    unsigned int u = __float_as_uint(f);
    unsigned int r = (u + 0x7FFFu + ((u >> 16) & 1u)) >> 16;
    return (unsigned short)r;
}
__device__ inline float bf2f(unsigned short h) {
    return __uint_as_float((unsigned int)h << 16);
}

// ---------------- token mean (two-stage) ----------------
__global__ void mean_partial(const float* __restrict__ g, float* __restrict__ part) {
    int b = blockIdx.x, t = blockIdx.y, c = threadIdx.x;
    const float* p = g + ((size_t)b * Ntok + (size_t)t * 48) * Cdim + c;
    float s = 0.f;
    #pragma unroll 4
    for (int n = 0; n < 48; ++n) s += p[(size_t)n * Cdim];
    part[((size_t)b * 40 + t) * Cdim + c] = s;
}

__global__ void mean_final(const float* __restrict__ part, float* __restrict__ meang) {
    int b = blockIdx.x, c = threadIdx.x;
    float s = 0.f;
    for (int t = 0; t < 40; ++t) s += part[((size_t)b * 40 + t) * Cdim + c];
    meang[b * Cdim + c] = s * (1.0f / (float)Ntok);
}

// ---------------- per-row inverse norm of g ----------------
__global__ void invnorm_k(const float* __restrict__ g, float* __restrict__ invn) {
    int wid = threadIdx.x >> 6, lane = threadIdx.x & 63;
    int row = blockIdx.x * 4 + wid;
    const float* p = g + (size_t)row * Cdim;
    float ss = 0.f;
    #pragma unroll
    for (int i = lane; i < Cdim; i += 64) { float v = p[i]; ss += v * v; }
    #pragma unroll
    for (int o = 1; o < 64; o <<= 1) ss += __shfl_xor(ss, o);
    if (lane == 0) {
        float n = sqrtf(ss);
        invn[row] = 1.0f / fmaxf(n, 1e-12f);
    }
}

// ---------------- f32 -> (hi,lo) bf16 split, optional per-token bias ----------------
// One float4 per thread. bias (meang) indexed as [(elem / (Ntok*Cdim))*Cdim + elem%Cdim].
__global__ void split_k(const float* __restrict__ src, const float* __restrict__ bias,
                        unsigned short* __restrict__ hi, unsigned short* __restrict__ lo,
                        int n4) {
    int i = blockIdx.x * 256 + threadIdx.x;
    if (i >= n4) return;
    float4 v = ((const float4*)src)[i];
    if (bias) {
        int b  = i / (Ntok * Cdim / 4);
        int c4 = (i & (Cdim / 4 - 1)) << 2;
        float4 bv = *(const float4*)&bias[b * Cdim + c4];
        v.x += bv.x; v.y += bv.y; v.z += bv.z; v.w += bv.w;
    }
    ushort4 h, l;
    h.x = f2bf(v.x); l.x = f2bf(v.x - bf2f(h.x));
    h.y = f2bf(v.y); l.y = f2bf(v.y - bf2f(h.y));
    h.z = f2bf(v.z); l.z = f2bf(v.z - bf2f(h.z));
    h.w = f2bf(v.w); l.w = f2bf(v.w - bf2f(h.w));
    ((ushort4*)hi)[i] = h;
    ((ushort4*)lo)[i] = l;
}

// ---------------- split-bf16 MFMA GEMM ----------------
// Computes O = alpha * rs*cs * (A · op(B)) with A ≈ Ahi+Alo, B ≈ Bhi+Blo,
// acc = Ah·Bh + Ah·Bl + Al·Bh (f32 MFMA accumulation).
// NT (NN=false): B stored [N,K] row-major (k-contiguous) -> O = A·B^T.
// NN (NN=true):  B stored [K,N] row-major               -> O = A·B.
// Output: either f32 (Of32) or split bf16 (Ohi/Olo). Batched over blockIdx.z.
template<bool NN>
__global__ __launch_bounds__(256) void mfma_gemm(
    const unsigned short* __restrict__ Ahi, const unsigned short* __restrict__ Alo,
    const unsigned short* __restrict__ Bhi, const unsigned short* __restrict__ Blo,
    float* __restrict__ Of32, unsigned short* __restrict__ Ohi, unsigned short* __restrict__ Olo,
    int M, int N, int K,
    long aB, long bB, long oB,
    float alpha, const float* __restrict__ rs, const float* __restrict__ cs, int sB)
{
    int z = blockIdx.z;
    const unsigned short* Ah = Ahi + (size_t)z * aB;
    const unsigned short* Al = Alo + (size_t)z * aB;
    const unsigned short* Bh = Bhi + (size_t)z * bB;
    const unsigned short* Bl = Blo + (size_t)z * bB;

    int m0 = blockIdx.y * 128, n0 = blockIdx.x * 128;

    // stride 40 shorts = 80 B: keeps 16B alignment, breaks pow2 bank pattern
    __shared__ __align__(16) unsigned short As_h[128 * 40];
    __shared__ __align__(16) unsigned short As_l[128 * 40];
    __shared__ __align__(16) unsigned short Bs_h[128 * 40];
    __shared__ __align__(16) unsigned short Bs_l[128 * 40];

    int tid  = threadIdx.x;
    int lane = tid & 63, wid = tid >> 6;
    int wm = (wid >> 1) * 64, wn = (wid & 1) * 64;

    f32x4 acc[4][4] = {};

    for (int k0 = 0; k0 < K; k0 += 32) {
        // ---- stage A tile (128 x 32), hi + lo ----
        #pragma unroll
        for (int it = 0; it < 2; ++it) {
            int idx = it * 256 + tid;
            int row = idx >> 2, kc = (idx & 3) << 3;
            int gr = min(m0 + row, M - 1);
            size_t go = (size_t)gr * K + k0 + kc;
            *(uint4*)&As_h[row * 40 + kc] = *(const uint4*)&Ah[go];
            *(uint4*)&As_l[row * 40 + kc] = *(const uint4*)&Al[go];
        }
        // ---- stage B tile ----
        if (!NN) {
            #pragma unroll
            for (int it = 0; it < 2; ++it) {
                int idx = it * 256 + tid;
                int row = idx >> 2, kc = (idx & 3) << 3;
                int gc = min(n0 + row, N - 1);
                size_t go = (size_t)gc * K + k0 + kc;
                *(uint4*)&Bs_h[row * 40 + kc] = *(const uint4*)&Bh[go];
                *(uint4*)&Bs_l[row * 40 + kc] = *(const uint4*)&Bl[go];
            }
        } else {
            // B is [K,N]: transpose into Bs[n][k] with 8-wide XOR swizzle on k
            #pragma unroll
            for (int it = 0; it < 2; ++it) {
                int idx = it * 256 + tid;
                int kk = idx >> 4, n8 = (idx & 15) << 3;
                size_t go = (size_t)(k0 + kk) * N + n0 + n8;
                uint4 vh = *(const uint4*)&Bh[go];
                uint4 vl = *(const uint4*)&Bl[go];
                const unsigned short* ph = (const unsigned short*)&vh;
                const unsigned short* pl = (const unsigned short*)&vl;
                #pragma unroll
                for (int j = 0; j < 8; ++j) {
                    int rr  = n8 + j;
                    int kks = kk ^ (((rr >> 3) & 3) << 3);
                    Bs_h[rr * 40 + kks] = ph[j];
                    Bs_l[rr * 40 + kks] = pl[j];
                }
            }
        }
        __syncthreads();

        int fr = lane & 15, kg = (lane >> 4) << 3;
        bf16x8 ah[4], al[4], bh[4], bl[4];
        #pragma unroll
        for (int f = 0; f < 4; ++f) {
            int ar = wm + f * 16 + fr;
            ah[f] = *(const bf16x8*)&As_h[ar * 40 + kg];
            al[f] = *(const bf16x8*)&As_l[ar * 40 + kg];
            int br = wn + f * 16 + fr;
            int kgb = NN ? (kg ^ (((br >> 3) & 3) << 3)) : kg;
            bh[f] = *(const bf16x8*)&Bs_h[br * 40 + kgb];
            bl[f] = *(const bf16x8*)&Bs_l[br * 40 + kgb];
        }
        #pragma unroll
        for (int i = 0; i < 4; ++i)
            #pragma unroll
            for (int j = 0; j < 4; ++j) {
                acc[i][j] = __builtin_amdgcn_mfma_f32_16x16x32_bf16(ah[i], bh[j], acc[i][j], 0, 0, 0);
                acc[i][j] = __builtin_amdgcn_mfma_f32_16x16x32_bf16(ah[i], bl[j], acc[i][j], 0, 0, 0);
                acc[i][j] = __builtin_amdgcn_mfma_f32_16x16x32_bf16(al[i], bh[j], acc[i][j], 0, 0, 0);
            }
        __syncthreads();
    }

    // ---- epilogue ----
    float* O          = Of32 ? Of32 + (size_t)z * oB : nullptr;
    unsigned short* OH = Ohi ? Ohi + (size_t)z * oB : nullptr;
    unsigned short* OL = Olo ? Olo + (size_t)z * oB : nullptr;
    int fr = lane & 15, fq = lane >> 4;
    #pragma unroll
    for (int i = 0; i < 4; ++i) {
        #pragma unroll
        for (int r = 0; r < 4; ++r) {
            int gm = m0 + wm + i * 16 + fq * 4 + r;
            if (gm >= M) continue;
            float rf = alpha * (rs ? rs[(size_t)z * sB + gm] : 1.0f);
            #pragma unroll
            for (int j = 0; j < 4; ++j) {
                int gn = n0 + wn + j * 16 + fr;
                if (gn >= N) continue;
                float v = acc[i][j][r] * rf * (cs ? cs[(size_t)z * sB + gn] : 1.0f);
                size_t off = (size_t)gm * N + gn;
                if (O) O[off] = v;
                else {
                    unsigned short h = f2bf(v);
                    OH[off] = h;
                    OL[off] = f2bf(v - bf2f(h));
                }
            }
        }
    }
}

// ---------------- row softmax with split-bf16 output ----------------
__global__ __launch_bounds__(256) void softmax_split(
    const float* __restrict__ S, unsigned short* __restrict__ Phi,
    unsigned short* __restrict__ Plo, int cols)
{
    __shared__ float buf[1920];
    __shared__ float red[4];
    size_t row = blockIdx.x;
    const float* p = S + row * (size_t)cols;
    int tid = threadIdx.x;

    float lmax = -1e30f;
    for (int c = tid; c < cols; c += 256) { float v = p[c]; buf[c] = v; lmax = fmaxf(lmax, v); }
    #pragma unroll
    for (int o = 1; o < 64; o <<= 1) lmax = fmaxf(lmax, __shfl_xor(lmax, o));
    if ((tid & 63) == 0) red[tid >> 6] = lmax;
    __syncthreads();
    float bmax = fmaxf(fmaxf(red[0], red[1]), fmaxf(red[2], red[3]));

    float lsum = 0.f;
    for (int c = tid; c < cols; c += 256) { float e = expf(buf[c] - bmax); buf[c] = e; lsum += e; }
    #pragma unroll
    for (int o = 1; o < 64; o <<= 1) lsum += __shfl_xor(lsum, o);
    __syncthreads();
    if ((tid & 63) == 0) red[tid >> 6] = lsum;
    __syncthreads();
    float inv = 1.0f / (red[0] + red[1] + red[2] + red[3]);
    unsigned short* ph = Phi + row * (size_t)cols;
    unsigned short* pl = Plo + row * (size_t)cols;
    for (int c = tid; c < cols; c += 256) {
        float v = buf[c] * inv;
        unsigned short h = f2bf(v);
        ph[c] = h;
        pl[c] = f2bf(v - bf2f(h));
    }
}

// ---------------- launch ----------------
extern "C" void kernel_launch(void* const* d_in, const int* in_sizes, int n_in,
                              void* d_out, int out_size, void* d_ws, size_t ws_size,
                              hipStream_t stream) {
    (void)in_sizes; (void)n_in; (void)out_size; (void)ws_size;
    const float* x  = (const float*)d_in[0];
    const float* g  = (const float*)d_in[1];
    const float* Wq = (const float*)d_in[2];
    const float* Wg = (const float*)d_in[3];
    float* out = (float*)d_out;

    char* ws = (char*)d_ws;
    size_t off = 0;
    auto alloc = [&](size_t bytes) { char* p = ws + off; off += (bytes + 255) & ~(size_t)255; return p; };

    float* meang = (float*)alloc(Bsz * Cdim * 4);
    float* part  = (float*)alloc(Bsz * 40 * Cdim * 4);
    float* invn  = (float*)alloc(Mrows * 4);
    const size_t GE = (size_t)Mrows * Cdim;          // 7864320 elems
    unsigned short* ghi  = (unsigned short*)alloc(GE * 2);
    unsigned short* glo  = (unsigned short*)alloc(GE * 2);
    unsigned short* qhi  = (unsigned short*)alloc(GE * 2);
    unsigned short* qlo  = (unsigned short*)alloc(GE * 2);
    unsigned short* wqhi = (unsigned short*)alloc(Cdim * Cdim * 2);
    unsigned short* wqlo = (unsigned short*)alloc(Cdim * Cdim * 2);
    unsigned short* wghi = (unsigned short*)alloc(Cdim * Cdim * 2);
    unsigned short* wglo = (unsigned short*)alloc(Cdim * Cdim * 2);
    unsigned short* rqhi = (unsigned short*)alloc(GE * 2);
    unsigned short* rqlo = (unsigned short*)alloc(GE * 2);
    unsigned short* rghi = (unsigned short*)alloc(GE * 2);
    unsigned short* rglo = (unsigned short*)alloc(GE * 2);
    unsigned short* g2hi = (unsigned short*)alloc(GE * 2);
    unsigned short* g2lo = (unsigned short*)alloc(GE * 2);
    unsigned short* pbhi = (unsigned short*)alloc((size_t)NBLK * BLK * BLK * 2);
    unsigned short* pblo = (unsigned short*)alloc((size_t)NBLK * BLK * BLK * 2);
    float* sc = (float*)alloc((size_t)Ntok * Ntok * 4);
    unsigned short* p2hi = (unsigned short*)alloc((size_t)Ntok * Ntok * 2);
    unsigned short* p2lo = (unsigned short*)alloc((size_t)Ntok * Ntok * 2);

    // 1. token mean of g; per-row inv norms
    mean_partial<<<dim3(Bsz, 40), 512, 0, stream>>>(g, part);
    mean_final<<<Bsz, 512, 0, stream>>>(part, meang);
    invnorm_k<<<Mrows / 4, 256, 0, stream>>>(g, invn);

    // 2. hi/lo splits
    split_k<<<(int)(GE / 4 + 255) / 256, 256, 0, stream>>>(g, nullptr, ghi, glo, (int)(GE / 4));
    split_k<<<(int)(GE / 4 + 255) / 256, 256, 0, stream>>>(x, meang, qhi, qlo, (int)(GE / 4));
    split_k<<<(Cdim * Cdim / 4) / 256, 256, 0, stream>>>(Wq, nullptr, wqhi, wqlo, Cdim * Cdim / 4);
    split_k<<<(Cdim * Cdim / 4) / 256, 256, 0, stream>>>(Wg, nullptr, wghi, wglo, Cdim * Cdim / 4);

    // 3. rel_q = q @ Wq^T  -> split   [15360,512]
    mfma_gemm<false><<<dim3(Cdim / 128, Mrows / 128), 256, 0, stream>>>(
        qhi, qlo, wqhi, wqlo, nullptr, rqhi, rqlo,
        Mrows, Cdim, Cdim, 0, 0, 0, 1.0f, nullptr, nullptr, 0);

    // 4. block scores = (g·g^T)*invn_i*invn_j*SCALE -> f32 (sc reused)   [80][192][192]
    mfma_gemm<false><<<dim3(2, 2, NBLK), 256, 0, stream>>>(
        ghi, glo, ghi, glo, sc, nullptr, nullptr,
        BLK, BLK, Cdim, (long)BLK * Cdim, (long)BLK * Cdim, (long)BLK * BLK,
        SCALE, invn, invn, BLK);

    // 5. block softmax -> split probs
    softmax_split<<<NBLK * BLK, 256, 0, stream>>>(sc, pbhi, pblo, BLK);

    // 6. g2 = attn @ gb -> split   [80][192][512]
    mfma_gemm<true><<<dim3(Cdim / 128, 2, NBLK), 256, 0, stream>>>(
        pbhi, pblo, ghi, glo, nullptr, g2hi, g2lo,
        BLK, Cdim, BLK, (long)BLK * BLK, (long)BLK * Cdim, (long)BLK * Cdim,
        1.0f, nullptr, nullptr, 0);

    // 7. rel_g = g2 @ Wg^T -> split   [15360,512]
    mfma_gemm<false><<<dim3(Cdim / 128, Mrows / 128), 256, 0, stream>>>(
        g2hi, g2lo, wghi, wglo, nullptr, rghi, rglo,
        Mrows, Cdim, Cdim, 0, 0, 0, 1.0f, nullptr, nullptr, 0);

    // 8. per-batch global attention
    for (int b = 0; b < Bsz; ++b) {
        size_t o2 = (size_t)b * Ntok * Cdim;
        // scores2 = rel_q[b] @ rel_g[b]^T * SCALE -> f32 sc   [1920,1920]
        mfma_gemm<false><<<dim3(Ntok / 128, Ntok / 128), 256, 0, stream>>>(
            rqhi + o2, rqlo + o2, rghi + o2, rglo + o2, sc, nullptr, nullptr,
            Ntok, Ntok, Cdim, 0, 0, 0, SCALE, nullptr, nullptr, 0);
        // softmax rows -> split probs
        softmax_split<<<Ntok, 256, 0, stream>>>(sc, p2hi, p2lo, Ntok);
        // out[b] = attn2 @ g2[b] -> f32   [1920,512]
        mfma_gemm<true><<<dim3(Cdim / 128, Ntok / 128), 256, 0, stream>>>(
            p2hi, p2lo, g2hi + o2, g2lo + o2, out + o2, nullptr, nullptr,
            Ntok, Cdim, Ntok, 0, 0, 0, 1.0f, nullptr, nullptr, 0);
    }
}

// Round 3
// 640.971 us; speedup vs baseline: 4.0790x; 2.0929x over previous
//
#include <hip/hip_runtime.h>
#include <math.h>

// Problem constants
constexpr int Bsz  = 8;
constexpr int Ntok = 1920;
constexpr int Cdim = 512;
constexpr int BLK  = 192;
constexpr int Mrows = Bsz * Ntok;      // 15360
constexpr int NBLK  = Mrows / BLK;     // 80
constexpr float SCALE = 0.02209708691207961f;  // 2048^-0.5

typedef __bf16 bf16x8 __attribute__((ext_vector_type(8)));
typedef float  f32x4  __attribute__((ext_vector_type(4)));

// ---- bf16 helpers (RNE, finite values only) ----
__device__ inline unsigned short f2bf(float f) {
    unsigned int u = __float_as_uint(f);
    unsigned int r = (u + 0x7FFFu + ((u >> 16) & 1u)) >> 16;
    return (unsigned short)r;
}
__device__ inline float bf2f(unsigned short h) {
    return __uint_as_float((unsigned int)h << 16);
}

// ---------------- token mean (two-stage) ----------------
__global__ void mean_partial(const float* __restrict__ g, float* __restrict__ part) {
    int b = blockIdx.x, t = blockIdx.y, c = threadIdx.x;
    const float* p = g + ((size_t)b * Ntok + (size_t)t * 48) * Cdim + c;
    float s = 0.f;
    #pragma unroll 4
    for (int n = 0; n < 48; ++n) s += p[(size_t)n * Cdim];
    part[((size_t)b * 40 + t) * Cdim + c] = s;
}

__global__ void mean_final(const float* __restrict__ part, float* __restrict__ meang) {
    int b = blockIdx.x, c = threadIdx.x;
    float s = 0.f;
    for (int t = 0; t < 40; ++t) s += part[((size_t)b * 40 + t) * Cdim + c];
    meang[b * Cdim + c] = s * (1.0f / (float)Ntok);
}

// ---------------- per-row inverse norm of g ----------------
__global__ void invnorm_k(const float* __restrict__ g, float* __restrict__ invn) {
    int wid = threadIdx.x >> 6, lane = threadIdx.x & 63;
    int row = blockIdx.x * 4 + wid;
    const float* p = g + (size_t)row * Cdim;
    float ss = 0.f;
    #pragma unroll
    for (int i = lane; i < Cdim; i += 64) { float v = p[i]; ss += v * v; }
    #pragma unroll
    for (int o = 1; o < 64; o <<= 1) ss += __shfl_xor(ss, o);
    if (lane == 0) {
        float n = sqrtf(ss);
        invn[row] = 1.0f / fmaxf(n, 1e-12f);
    }
}

// ---------------- f32 -> (hi,lo) bf16 split, optional per-token bias ----------------
__global__ void split_k(const float* __restrict__ src, const float* __restrict__ bias,
                        unsigned short* __restrict__ hi, unsigned short* __restrict__ lo,
                        int n4) {
    int i = blockIdx.x * 256 + threadIdx.x;
    if (i >= n4) return;
    float4 v = ((const float4*)src)[i];
    if (bias) {
        int b  = i / (Ntok * Cdim / 4);
        int c4 = (i & (Cdim / 4 - 1)) << 2;
        float4 bv = *(const float4*)&bias[b * Cdim + c4];
        v.x += bv.x; v.y += bv.y; v.z += bv.z; v.w += bv.w;
    }
    ushort4 h, l;
    h.x = f2bf(v.x); l.x = f2bf(v.x - bf2f(h.x));
    h.y = f2bf(v.y); l.y = f2bf(v.y - bf2f(h.y));
    h.z = f2bf(v.z); l.z = f2bf(v.z - bf2f(h.z));
    h.w = f2bf(v.w); l.w = f2bf(v.w - bf2f(h.w));
    ((ushort4*)hi)[i] = h;
    ((ushort4*)lo)[i] = l;
}

// ---------------- split-bf16 MFMA GEMM ----------------
// O = alpha * rs*cs * (A · op(B)); A ≈ Ahi+Alo, B ≈ Bhi+Blo;
// acc = Ah·Bh + Ah·Bl + Al·Bh (f32 accumulation; drops only Al·Bl ~ 2^-16 rel).
// NT (NN=false): B stored [N,K] row-major -> O = A·B^T.
// NN (NN=true):  B stored [K,N] row-major -> O = A·B.
// Output: f32 (Of32) or split bf16 (Ohi/Olo). Batched over blockIdx.z.
template<bool NN>
__global__ __launch_bounds__(256) void mfma_gemm(
    const unsigned short* __restrict__ Ahi, const unsigned short* __restrict__ Alo,
    const unsigned short* __restrict__ Bhi, const unsigned short* __restrict__ Blo,
    float* __restrict__ Of32, unsigned short* __restrict__ Ohi, unsigned short* __restrict__ Olo,
    int M, int N, int K,
    long aB, long bB, long oB,
    float alpha, const float* __restrict__ rs, const float* __restrict__ cs, int sB)
{
    int z = blockIdx.z;
    const unsigned short* Ah = Ahi + (size_t)z * aB;
    const unsigned short* Al = Alo + (size_t)z * aB;
    const unsigned short* Bh = Bhi + (size_t)z * bB;
    const unsigned short* Bl = Blo + (size_t)z * bB;

    int m0 = blockIdx.y * 128, n0 = blockIdx.x * 128;

    __shared__ __align__(16) unsigned short As_h[128 * 40];
    __shared__ __align__(16) unsigned short As_l[128 * 40];
    __shared__ __align__(16) unsigned short Bs_h[128 * 40];
    __shared__ __align__(16) unsigned short Bs_l[128 * 40];

    int tid  = threadIdx.x;
    int lane = tid & 63, wid = tid >> 6;
    int wm = (wid >> 1) * 64, wn = (wid & 1) * 64;

    f32x4 acc[4][4] = {};

    for (int k0 = 0; k0 < K; k0 += 32) {
        #pragma unroll
        for (int it = 0; it < 2; ++it) {
            int idx = it * 256 + tid;
            int row = idx >> 2, kc = (idx & 3) << 3;
            int gr = min(m0 + row, M - 1);
            size_t go = (size_t)gr * K + k0 + kc;
            *(uint4*)&As_h[row * 40 + kc] = *(const uint4*)&Ah[go];
            *(uint4*)&As_l[row * 40 + kc] = *(const uint4*)&Al[go];
        }
        if (!NN) {
            #pragma unroll
            for (int it = 0; it < 2; ++it) {
                int idx = it * 256 + tid;
                int row = idx >> 2, kc = (idx & 3) << 3;
                int gc = min(n0 + row, N - 1);
                size_t go = (size_t)gc * K + k0 + kc;
                *(uint4*)&Bs_h[row * 40 + kc] = *(const uint4*)&Bh[go];
                *(uint4*)&Bs_l[row * 40 + kc] = *(const uint4*)&Bl[go];
            }
        } else {
            #pragma unroll
            for (int it = 0; it < 2; ++it) {
                int idx = it * 256 + tid;
                int kk = idx >> 4, n8 = (idx & 15) << 3;
                size_t go = (size_t)(k0 + kk) * N + n0 + n8;
                uint4 vh = *(const uint4*)&Bh[go];
                uint4 vl = *(const uint4*)&Bl[go];
                const unsigned short* ph = (const unsigned short*)&vh;
                const unsigned short* pl = (const unsigned short*)&vl;
                #pragma unroll
                for (int j = 0; j < 8; ++j) {
                    int rr  = n8 + j;
                    int kks = kk ^ (((rr >> 3) & 3) << 3);
                    Bs_h[rr * 40 + kks] = ph[j];
                    Bs_l[rr * 40 + kks] = pl[j];
                }
            }
        }
        __syncthreads();

        int fr = lane & 15, kg = (lane >> 4) << 3;
        bf16x8 ah[4], al[4], bh[4], bl[4];
        #pragma unroll
        for (int f = 0; f < 4; ++f) {
            int ar = wm + f * 16 + fr;
            ah[f] = *(const bf16x8*)&As_h[ar * 40 + kg];
            al[f] = *(const bf16x8*)&As_l[ar * 40 + kg];
            int br = wn + f * 16 + fr;
            int kgb = NN ? (kg ^ (((br >> 3) & 3) << 3)) : kg;
            bh[f] = *(const bf16x8*)&Bs_h[br * 40 + kgb];
            bl[f] = *(const bf16x8*)&Bs_l[br * 40 + kgb];
        }
        #pragma unroll
        for (int i = 0; i < 4; ++i)
            #pragma unroll
            for (int j = 0; j < 4; ++j) {
                acc[i][j] = __builtin_amdgcn_mfma_f32_16x16x32_bf16(ah[i], bh[j], acc[i][j], 0, 0, 0);
                acc[i][j] = __builtin_amdgcn_mfma_f32_16x16x32_bf16(ah[i], bl[j], acc[i][j], 0, 0, 0);
                acc[i][j] = __builtin_amdgcn_mfma_f32_16x16x32_bf16(al[i], bh[j], acc[i][j], 0, 0, 0);
            }
        __syncthreads();
    }

    float* O           = Of32 ? Of32 + (size_t)z * oB : nullptr;
    unsigned short* OH = Ohi ? Ohi + (size_t)z * oB : nullptr;
    unsigned short* OL = Olo ? Olo + (size_t)z * oB : nullptr;
    int fr = lane & 15, fq = lane >> 4;
    #pragma unroll
    for (int i = 0; i < 4; ++i) {
        #pragma unroll
        for (int r = 0; r < 4; ++r) {
            int gm = m0 + wm + i * 16 + fq * 4 + r;
            if (gm >= M) continue;
            float rf = alpha * (rs ? rs[(size_t)z * sB + gm] : 1.0f);
            #pragma unroll
            for (int j = 0; j < 4; ++j) {
                int gn = n0 + wn + j * 16 + fr;
                if (gn >= N) continue;
                float v = acc[i][j][r] * rf * (cs ? cs[(size_t)z * sB + gn] : 1.0f);
                size_t off = (size_t)gm * N + gn;
                if (O) O[off] = v;
                else {
                    unsigned short h = f2bf(v);
                    OH[off] = h;
                    OL[off] = f2bf(v - bf2f(h));
                }
            }
        }
    }
}

// ---------------- in-place row softmax on split-bf16 scores ----------------
// Reads v = hi+lo per element, softmax over the row, writes prob hi/lo back.
__global__ __launch_bounds__(256) void softmax_inplace(
    unsigned short* __restrict__ Phi, unsigned short* __restrict__ Plo, int cols)
{
    __shared__ float buf[1920];
    __shared__ float red[4];
    size_t row = blockIdx.x;
    unsigned short* ph = Phi + row * (size_t)cols;
    unsigned short* pl = Plo + row * (size_t)cols;
    int tid = threadIdx.x;
    int nq = cols >> 2;

    float lmax = -1e30f;
    for (int q = tid; q < nq; q += 256) {
        ushort4 h = ((const ushort4*)ph)[q];
        ushort4 l = ((const ushort4*)pl)[q];
        float v0 = bf2f(h.x) + bf2f(l.x);
        float v1 = bf2f(h.y) + bf2f(l.y);
        float v2 = bf2f(h.z) + bf2f(l.z);
        float v3 = bf2f(h.w) + bf2f(l.w);
        buf[q * 4 + 0] = v0; buf[q * 4 + 1] = v1;
        buf[q * 4 + 2] = v2; buf[q * 4 + 3] = v3;
        lmax = fmaxf(lmax, fmaxf(fmaxf(v0, v1), fmaxf(v2, v3)));
    }
    #pragma unroll
    for (int o = 1; o < 64; o <<= 1) lmax = fmaxf(lmax, __shfl_xor(lmax, o));
    if ((tid & 63) == 0) red[tid >> 6] = lmax;
    __syncthreads();
    float bmax = fmaxf(fmaxf(red[0], red[1]), fmaxf(red[2], red[3]));

    float lsum = 0.f;
    for (int c = tid; c < cols; c += 256) {
        float e = expf(buf[c] - bmax);
        buf[c] = e;
        lsum += e;
    }
    #pragma unroll
    for (int o = 1; o < 64; o <<= 1) lsum += __shfl_xor(lsum, o);
    __syncthreads();
    if ((tid & 63) == 0) red[tid >> 6] = lsum;
    __syncthreads();
    float inv = 1.0f / (red[0] + red[1] + red[2] + red[3]);

    for (int q = tid; q < nq; q += 256) {
        float v0 = buf[q * 4 + 0] * inv;
        float v1 = buf[q * 4 + 1] * inv;
        float v2 = buf[q * 4 + 2] * inv;
        float v3 = buf[q * 4 + 3] * inv;
        ushort4 h, l;
        h.x = f2bf(v0); l.x = f2bf(v0 - bf2f(h.x));
        h.y = f2bf(v1); l.y = f2bf(v1 - bf2f(h.y));
        h.z = f2bf(v2); l.z = f2bf(v2 - bf2f(h.z));
        h.w = f2bf(v3); l.w = f2bf(v3 - bf2f(h.w));
        ((ushort4*)ph)[q] = h;
        ((ushort4*)pl)[q] = l;
    }
}

// ---------------- launch ----------------
extern "C" void kernel_launch(void* const* d_in, const int* in_sizes, int n_in,
                              void* d_out, int out_size, void* d_ws, size_t ws_size,
                              hipStream_t stream) {
    (void)in_sizes; (void)n_in; (void)out_size;
    const float* x  = (const float*)d_in[0];
    const float* g  = (const float*)d_in[1];
    const float* Wq = (const float*)d_in[2];
    const float* Wg = (const float*)d_in[3];
    float* out = (float*)d_out;

    const size_t GE = (size_t)Mrows * Cdim;      // 7,864,320 elems
    auto rnd = [](size_t b) { return (b + 255) & ~(size_t)255; };

    // pick largest chunk CH of batches for the global-attention score scratch
    auto need = [&](int CH) -> size_t {
        size_t t = 0;
        t += rnd(Bsz * Cdim * 4) + rnd(Bsz * 40 * Cdim * 4) + rnd(Mrows * 4);
        t += 4 * rnd(GE * 2);                        // ghi glo qhi qlo
        t += 4 * rnd((size_t)Cdim * Cdim * 2);       // wq wg hi/lo
        t += 6 * rnd(GE * 2);                        // rq rg g2 hi/lo
        t += 2 * rnd((size_t)NBLK * BLK * BLK * 2);  // block scores/probs hi/lo
        t += 2 * rnd((size_t)CH * Ntok * Ntok * 2);  // global scores/probs hi/lo
        return t;
    };
    int CH = 8;
    while (CH > 1 && need(CH) > ws_size) CH >>= 1;

    char* ws = (char*)d_ws;
    size_t off = 0;
    auto alloc = [&](size_t bytes) { char* p = ws + off; off += rnd(bytes); return p; };

    float* meang = (float*)alloc(Bsz * Cdim * 4);
    float* part  = (float*)alloc(Bsz * 40 * Cdim * 4);
    float* invn  = (float*)alloc(Mrows * 4);
    unsigned short* ghi  = (unsigned short*)alloc(GE * 2);
    unsigned short* glo  = (unsigned short*)alloc(GE * 2);
    unsigned short* qhi  = (unsigned short*)alloc(GE * 2);
    unsigned short* qlo  = (unsigned short*)alloc(GE * 2);
    unsigned short* wqhi = (unsigned short*)alloc((size_t)Cdim * Cdim * 2);
    unsigned short* wqlo = (unsigned short*)alloc((size_t)Cdim * Cdim * 2);
    unsigned short* wghi = (unsigned short*)alloc((size_t)Cdim * Cdim * 2);
    unsigned short* wglo = (unsigned short*)alloc((size_t)Cdim * Cdim * 2);
    unsigned short* rqhi = (unsigned short*)alloc(GE * 2);
    unsigned short* rqlo = (unsigned short*)alloc(GE * 2);
    unsigned short* rghi = (unsigned short*)alloc(GE * 2);
    unsigned short* rglo = (unsigned short*)alloc(GE * 2);
    unsigned short* g2hi = (unsigned short*)alloc(GE * 2);
    unsigned short* g2lo = (unsigned short*)alloc(GE * 2);
    unsigned short* sbhi = (unsigned short*)alloc((size_t)NBLK * BLK * BLK * 2);
    unsigned short* sblo = (unsigned short*)alloc((size_t)NBLK * BLK * BLK * 2);
    unsigned short* s2hi = (unsigned short*)alloc((size_t)CH * Ntok * Ntok * 2);
    unsigned short* s2lo = (unsigned short*)alloc((size_t)CH * Ntok * Ntok * 2);

    // 1. token mean of g; per-row inv norms
    mean_partial<<<dim3(Bsz, 40), 512, 0, stream>>>(g, part);
    mean_final<<<Bsz, 512, 0, stream>>>(part, meang);
    invnorm_k<<<Mrows / 4, 256, 0, stream>>>(g, invn);

    // 2. hi/lo splits
    split_k<<<(int)(GE / 4 + 255) / 256, 256, 0, stream>>>(g, nullptr, ghi, glo, (int)(GE / 4));
    split_k<<<(int)(GE / 4 + 255) / 256, 256, 0, stream>>>(x, meang, qhi, qlo, (int)(GE / 4));
    split_k<<<(Cdim * Cdim / 4) / 256, 256, 0, stream>>>(Wq, nullptr, wqhi, wqlo, Cdim * Cdim / 4);
    split_k<<<(Cdim * Cdim / 4) / 256, 256, 0, stream>>>(Wg, nullptr, wghi, wglo, Cdim * Cdim / 4);

    // 3. rel_q = q @ Wq^T  -> split  [15360,512]
    mfma_gemm<false><<<dim3(Cdim / 128, Mrows / 128), 256, 0, stream>>>(
        qhi, qlo, wqhi, wqlo, nullptr, rqhi, rqlo,
        Mrows, Cdim, Cdim, 0, 0, 0, 1.0f, nullptr, nullptr, 0);

    // 4. block scores = (g·g^T)*invn_i*invn_j*SCALE -> split in place  [80][192][192]
    mfma_gemm<false><<<dim3(2, 2, NBLK), 256, 0, stream>>>(
        ghi, glo, ghi, glo, nullptr, sbhi, sblo,
        BLK, BLK, Cdim, (long)BLK * Cdim, (long)BLK * Cdim, (long)BLK * BLK,
        SCALE, invn, invn, BLK);

    // 5. block softmax in place
    softmax_inplace<<<NBLK * BLK, 256, 0, stream>>>(sbhi, sblo, BLK);

    // 6. g2 = attn @ gb -> split  [80][192][512]
    mfma_gemm<true><<<dim3(Cdim / 128, 2, NBLK), 256, 0, stream>>>(
        sbhi, sblo, ghi, glo, nullptr, g2hi, g2lo,
        BLK, Cdim, BLK, (long)BLK * BLK, (long)BLK * Cdim, (long)BLK * Cdim,
        1.0f, nullptr, nullptr, 0);

    // 7. rel_g = g2 @ Wg^T -> split  [15360,512]
    mfma_gemm<false><<<dim3(Cdim / 128, Mrows / 128), 256, 0, stream>>>(
        g2hi, g2lo, wghi, wglo, nullptr, rghi, rglo,
        Mrows, Cdim, Cdim, 0, 0, 0, 1.0f, nullptr, nullptr, 0);

    // 8. global attention, CH batches per chunk (batched grids for occupancy)
    for (int c0 = 0; c0 < Bsz; c0 += CH) {
        size_t o2 = (size_t)c0 * Ntok * Cdim;
        // scores2 = rel_q @ rel_g^T * SCALE -> split  [CH][1920][1920]
        mfma_gemm<false><<<dim3(Ntok / 128, Ntok / 128, CH), 256, 0, stream>>>(
            rqhi + o2, rqlo + o2, rghi + o2, rglo + o2, nullptr, s2hi, s2lo,
            Ntok, Ntok, Cdim,
            (long)Ntok * Cdim, (long)Ntok * Cdim, (long)Ntok * Ntok,
            SCALE, nullptr, nullptr, 0);
        // softmax in place
        softmax_inplace<<<CH * Ntok, 256, 0, stream>>>(s2hi, s2lo, Ntok);
        // out = attn2 @ g2 -> f32  [CH][1920][512]
        mfma_gemm<true><<<dim3(Cdim / 128, Ntok / 128, CH), 256, 0, stream>>>(
            s2hi, s2lo, g2hi + o2, g2lo + o2, out + o2, nullptr, nullptr,
            Ntok, Cdim, Ntok,
            (long)Ntok * Ntok, (long)Ntok * Cdim, (long)Ntok * Cdim,
            1.0f, nullptr, nullptr, 0);
    }
}

// Round 4
// 627.057 us; speedup vs baseline: 4.1696x; 1.0222x over previous
//
#include <hip/hip_runtime.h>
#include <math.h>

// Problem constants
constexpr int Bsz  = 8;
constexpr int Ntok = 1920;
constexpr int Cdim = 512;
constexpr int BLK  = 192;
constexpr int Mrows = Bsz * Ntok;      // 15360
constexpr int NBLK  = Mrows / BLK;     // 80
constexpr float SCALE = 0.02209708691207961f;  // 2048^-0.5

typedef __bf16 bf16x8 __attribute__((ext_vector_type(8)));
typedef float  f32x4  __attribute__((ext_vector_type(4)));

// LDS plane geometry: operand tile 128 rows x 32 k  ->  4 planes [kg][row][8 bf16]
// plane stride 1040 shorts = 2080 B (2048 + 32 pad): staging writes 2-way max, reads contiguous.
constexpr int PS = 1040;

// ---- bf16 helpers (RNE, finite values only) ----
__device__ inline unsigned short f2bf(float f) {
    unsigned int u = __float_as_uint(f);
    unsigned int r = (u + 0x7FFFu + ((u >> 16) & 1u)) >> 16;
    return (unsigned short)r;
}
__device__ inline float bf2f(unsigned short h) {
    return __uint_as_float((unsigned int)h << 16);
}

// ---------------- token mean (two-stage) ----------------
__global__ void mean_partial(const float* __restrict__ g, float* __restrict__ part) {
    int b = blockIdx.x, t = blockIdx.y, c = threadIdx.x;
    const float* p = g + ((size_t)b * Ntok + (size_t)t * 48) * Cdim + c;
    float s = 0.f;
    #pragma unroll 4
    for (int n = 0; n < 48; ++n) s += p[(size_t)n * Cdim];
    part[((size_t)b * 40 + t) * Cdim + c] = s;
}

__global__ void mean_final(const float* __restrict__ part, float* __restrict__ meang) {
    int b = blockIdx.x, c = threadIdx.x;
    float s = 0.f;
    for (int t = 0; t < 40; ++t) s += part[((size_t)b * 40 + t) * Cdim + c];
    meang[b * Cdim + c] = s * (1.0f / (float)Ntok);
}

// ---------------- per-row inverse norm of g ----------------
__global__ void invnorm_k(const float* __restrict__ g, float* __restrict__ invn) {
    int wid = threadIdx.x >> 6, lane = threadIdx.x & 63;
    int row = blockIdx.x * 4 + wid;
    const float* p = g + (size_t)row * Cdim;
    float ss = 0.f;
    #pragma unroll
    for (int i = lane; i < Cdim; i += 64) { float v = p[i]; ss += v * v; }
    #pragma unroll
    for (int o = 1; o < 64; o <<= 1) ss += __shfl_xor(ss, o);
    if (lane == 0) {
        float n = sqrtf(ss);
        invn[row] = 1.0f / fmaxf(n, 1e-12f);
    }
}

// ---------------- f32 -> (hi,lo) bf16 split, optional per-token bias ----------------
__global__ void split_k(const float* __restrict__ src, const float* __restrict__ bias,
                        unsigned short* __restrict__ hi, unsigned short* __restrict__ lo,
                        int n4) {
    int i = blockIdx.x * 256 + threadIdx.x;
    if (i >= n4) return;
    float4 v = ((const float4*)src)[i];
    if (bias) {
        int b  = i / (Ntok * Cdim / 4);
        int c4 = (i & (Cdim / 4 - 1)) << 2;
        float4 bv = *(const float4*)&bias[b * Cdim + c4];
        v.x += bv.x; v.y += bv.y; v.z += bv.z; v.w += bv.w;
    }
    ushort4 h, l;
    h.x = f2bf(v.x); l.x = f2bf(v.x - bf2f(h.x));
    h.y = f2bf(v.y); l.y = f2bf(v.y - bf2f(h.y));
    h.z = f2bf(v.z); l.z = f2bf(v.z - bf2f(h.z));
    h.w = f2bf(v.w); l.w = f2bf(v.w - bf2f(h.w));
    ((ushort4*)hi)[i] = h;
    ((ushort4*)lo)[i] = l;
}

// ---------------- batched 64x64-tiled u16 transpose (hi+lo together) ----------------
// in[z]: R x C row-major -> out[z]: C x R row-major.
__global__ __launch_bounds__(256) void transpose2(
    const unsigned short* __restrict__ ih, const unsigned short* __restrict__ il,
    unsigned short* __restrict__ oh, unsigned short* __restrict__ ol,
    int R, int C, long inB, long outB)
{
    int z = blockIdx.z;
    ih += (size_t)z * inB;  il += (size_t)z * inB;
    oh += (size_t)z * outB; ol += (size_t)z * outB;
    __shared__ unsigned short th[64][68], tl[64][68];
    int r0 = blockIdx.y * 64, c0 = blockIdx.x * 64;
    int tr = threadIdx.x >> 4, tc = (threadIdx.x & 15) * 4;
    for (int rr = tr; rr < 64; rr += 16) {
        ushort4 h = *(const ushort4*)&ih[(size_t)(r0 + rr) * C + c0 + tc];
        ushort4 l = *(const ushort4*)&il[(size_t)(r0 + rr) * C + c0 + tc];
        th[tc + 0][rr] = h.x; th[tc + 1][rr] = h.y; th[tc + 2][rr] = h.z; th[tc + 3][rr] = h.w;
        tl[tc + 0][rr] = l.x; tl[tc + 1][rr] = l.y; tl[tc + 2][rr] = l.z; tl[tc + 3][rr] = l.w;
    }
    __syncthreads();
    for (int cc = tr; cc < 64; cc += 16) {
        ushort4 h = *(const ushort4*)&th[cc][tc];
        ushort4 l = *(const ushort4*)&tl[cc][tc];
        *(ushort4*)&oh[(size_t)(c0 + cc) * R + r0 + tc] = h;
        *(ushort4*)&ol[(size_t)(c0 + cc) * R + r0 + tc] = l;
    }
}

// ---------------- split-bf16 MFMA GEMM (NT only) ----------------
// O = alpha * rs*cs * (A · B^T); A [M,K], B [N,K] both k-contiguous row-major;
// A ≈ Ahi+Alo, B ≈ Bhi+Blo; acc = Ah·Bh + Ah·Bl + Al·Bh (f32 accumulation).
// Output: f32 (Of32) or split bf16 (Ohi/Olo). Batched over blockIdx.z.
__global__ __launch_bounds__(256) void mfma_gemm(
    const unsigned short* __restrict__ Ahi, const unsigned short* __restrict__ Alo,
    const unsigned short* __restrict__ Bhi, const unsigned short* __restrict__ Blo,
    float* __restrict__ Of32, unsigned short* __restrict__ Ohi, unsigned short* __restrict__ Olo,
    int M, int N, int K,
    long aB, long bB, long oB,
    float alpha, const float* __restrict__ rs, const float* __restrict__ cs, int sB)
{
    int z = blockIdx.z;
    const unsigned short* Ah = Ahi + (size_t)z * aB;
    const unsigned short* Al = Alo + (size_t)z * aB;
    const unsigned short* Bh = Bhi + (size_t)z * bB;
    const unsigned short* Bl = Blo + (size_t)z * bB;

    int m0 = blockIdx.y * 128, n0 = blockIdx.x * 128;

    // 4 k-planes per operand buffer, plane stride PS shorts (2080 B)
    __shared__ __align__(16) unsigned short As_h[4 * PS];
    __shared__ __align__(16) unsigned short As_l[4 * PS];
    __shared__ __align__(16) unsigned short Bs_h[4 * PS];
    __shared__ __align__(16) unsigned short Bs_l[4 * PS];

    int tid  = threadIdx.x;
    int lane = tid & 63, wid = tid >> 6;
    int wm = (wid >> 1) * 64, wn = (wid & 1) * 64;

    f32x4 acc[4][4] = {};

    for (int k0 = 0; k0 < K; k0 += 32) {
        // stage both tiles: idx -> (row = idx>>2, kg = idx&3); write (kg, row) 16B chunk
        #pragma unroll
        for (int it = 0; it < 2; ++it) {
            int idx = it * 256 + tid;
            int row = idx >> 2, kg = idx & 3;
            int lo = kg * PS + row * 8;
            {
                int gr = min(m0 + row, M - 1);
                size_t go = (size_t)gr * K + k0 + kg * 8;
                *(uint4*)&As_h[lo] = *(const uint4*)&Ah[go];
                *(uint4*)&As_l[lo] = *(const uint4*)&Al[go];
            }
            {
                int gc = min(n0 + row, N - 1);
                size_t go = (size_t)gc * K + k0 + kg * 8;
                *(uint4*)&Bs_h[lo] = *(const uint4*)&Bh[go];
                *(uint4*)&Bs_l[lo] = *(const uint4*)&Bl[go];
            }
        }
        __syncthreads();

        int fr = lane & 15, kg = lane >> 4;
        int pb = kg * PS + fr * 8;
        bf16x8 ah[4], al[4], bh[4], bl[4];
        #pragma unroll
        for (int f = 0; f < 4; ++f) {
            ah[f] = *(const bf16x8*)&As_h[pb + (wm + f * 16) * 8];
            al[f] = *(const bf16x8*)&As_l[pb + (wm + f * 16) * 8];
            bh[f] = *(const bf16x8*)&Bs_h[pb + (wn + f * 16) * 8];
            bl[f] = *(const bf16x8*)&Bs_l[pb + (wn + f * 16) * 8];
        }
        #pragma unroll
        for (int i = 0; i < 4; ++i)
            #pragma unroll
            for (int j = 0; j < 4; ++j) {
                acc[i][j] = __builtin_amdgcn_mfma_f32_16x16x32_bf16(ah[i], bh[j], acc[i][j], 0, 0, 0);
                acc[i][j] = __builtin_amdgcn_mfma_f32_16x16x32_bf16(ah[i], bl[j], acc[i][j], 0, 0, 0);
                acc[i][j] = __builtin_amdgcn_mfma_f32_16x16x32_bf16(al[i], bh[j], acc[i][j], 0, 0, 0);
            }
        __syncthreads();
    }

    float* O           = Of32 ? Of32 + (size_t)z * oB : nullptr;
    unsigned short* OH = Ohi ? Ohi + (size_t)z * oB : nullptr;
    unsigned short* OL = Olo ? Olo + (size_t)z * oB : nullptr;
    int fr = lane & 15, fq = lane >> 4;
    #pragma unroll
    for (int i = 0; i < 4; ++i) {
        #pragma unroll
        for (int r = 0; r < 4; ++r) {
            int gm = m0 + wm + i * 16 + fq * 4 + r;
            if (gm >= M) continue;
            float rf = alpha * (rs ? rs[(size_t)z * sB + gm] : 1.0f);
            #pragma unroll
            for (int j = 0; j < 4; ++j) {
                int gn = n0 + wn + j * 16 + fr;
                if (gn >= N) continue;
                float v = acc[i][j][r] * rf * (cs ? cs[(size_t)z * sB + gn] : 1.0f);
                size_t off = (size_t)gm * N + gn;
                if (O) O[off] = v;
                else {
                    unsigned short h = f2bf(v);
                    OH[off] = h;
                    OL[off] = f2bf(v - bf2f(h));
                }
            }
        }
    }
}

// ---------------- in-place row softmax on split-bf16 scores ----------------
__global__ __launch_bounds__(256) void softmax_inplace(
    unsigned short* __restrict__ Phi, unsigned short* __restrict__ Plo, int cols)
{
    __shared__ float buf[1920];
    __shared__ float red[4];
    size_t row = blockIdx.x;
    unsigned short* ph = Phi + row * (size_t)cols;
    unsigned short* pl = Plo + row * (size_t)cols;
    int tid = threadIdx.x;
    int nq = cols >> 2;

    float lmax = -1e30f;
    for (int q = tid; q < nq; q += 256) {
        ushort4 h = ((const ushort4*)ph)[q];
        ushort4 l = ((const ushort4*)pl)[q];
        float v0 = bf2f(h.x) + bf2f(l.x);
        float v1 = bf2f(h.y) + bf2f(l.y);
        float v2 = bf2f(h.z) + bf2f(l.z);
        float v3 = bf2f(h.w) + bf2f(l.w);
        buf[q * 4 + 0] = v0; buf[q * 4 + 1] = v1;
        buf[q * 4 + 2] = v2; buf[q * 4 + 3] = v3;
        lmax = fmaxf(lmax, fmaxf(fmaxf(v0, v1), fmaxf(v2, v3)));
    }
    #pragma unroll
    for (int o = 1; o < 64; o <<= 1) lmax = fmaxf(lmax, __shfl_xor(lmax, o));
    if ((tid & 63) == 0) red[tid >> 6] = lmax;
    __syncthreads();
    float bmax = fmaxf(fmaxf(red[0], red[1]), fmaxf(red[2], red[3]));

    float lsum = 0.f;
    for (int c = tid; c < cols; c += 256) {
        float e = expf(buf[c] - bmax);
        buf[c] = e;
        lsum += e;
    }
    #pragma unroll
    for (int o = 1; o < 64; o <<= 1) lsum += __shfl_xor(lsum, o);
    __syncthreads();
    if ((tid & 63) == 0) red[tid >> 6] = lsum;
    __syncthreads();
    float inv = 1.0f / (red[0] + red[1] + red[2] + red[3]);

    for (int q = tid; q < nq; q += 256) {
        float v0 = buf[q * 4 + 0] * inv;
        float v1 = buf[q * 4 + 1] * inv;
        float v2 = buf[q * 4 + 2] * inv;
        float v3 = buf[q * 4 + 3] * inv;
        ushort4 h, l;
        h.x = f2bf(v0); l.x = f2bf(v0 - bf2f(h.x));
        h.y = f2bf(v1); l.y = f2bf(v1 - bf2f(h.y));
        h.z = f2bf(v2); l.z = f2bf(v2 - bf2f(h.z));
        h.w = f2bf(v3); l.w = f2bf(v3 - bf2f(h.w));
        ((ushort4*)ph)[q] = h;
        ((ushort4*)pl)[q] = l;
    }
}

// ---------------- launch ----------------
extern "C" void kernel_launch(void* const* d_in, const int* in_sizes, int n_in,
                              void* d_out, int out_size, void* d_ws, size_t ws_size,
                              hipStream_t stream) {
    (void)in_sizes; (void)n_in; (void)out_size;
    const float* x  = (const float*)d_in[0];
    const float* g  = (const float*)d_in[1];
    const float* Wq = (const float*)d_in[2];
    const float* Wg = (const float*)d_in[3];
    float* out = (float*)d_out;

    const size_t GE = (size_t)Mrows * Cdim;      // 7,864,320 elems
    auto rnd = [](size_t b) { return (b + 255) & ~(size_t)255; };

    auto need = [&](int CH) -> size_t {
        size_t t = 0;
        t += rnd(Bsz * Cdim * 4) + rnd(Bsz * 40 * Cdim * 4) + rnd(Mrows * 4);
        t += 4 * rnd(GE * 2);                        // g, q splits
        t += 4 * rnd((size_t)Cdim * Cdim * 2);       // weights
        t += 6 * rnd(GE * 2);                        // rq rg g2
        t += 2 * rnd(GE * 2);                        // gT
        t += 2 * rnd((size_t)NBLK * BLK * BLK * 2);  // block scores
        t += 2 * rnd((size_t)CH * Ntok * Ntok * 2);  // global scores
        return t;
    };
    int CH = 8;
    while (CH > 1 && need(CH) > ws_size) CH >>= 1;

    char* ws = (char*)d_ws;
    size_t off = 0;
    auto alloc = [&](size_t bytes) { char* p = ws + off; off += rnd(bytes); return p; };

    float* meang = (float*)alloc(Bsz * Cdim * 4);
    float* part  = (float*)alloc(Bsz * 40 * Cdim * 4);
    float* invn  = (float*)alloc(Mrows * 4);
    unsigned short* ghi  = (unsigned short*)alloc(GE * 2);
    unsigned short* glo  = (unsigned short*)alloc(GE * 2);
    unsigned short* qhi  = (unsigned short*)alloc(GE * 2);   // reused as g2T hi after step 3
    unsigned short* qlo  = (unsigned short*)alloc(GE * 2);   // reused as g2T lo after step 3
    unsigned short* wqhi = (unsigned short*)alloc((size_t)Cdim * Cdim * 2);
    unsigned short* wqlo = (unsigned short*)alloc((size_t)Cdim * Cdim * 2);
    unsigned short* wghi = (unsigned short*)alloc((size_t)Cdim * Cdim * 2);
    unsigned short* wglo = (unsigned short*)alloc((size_t)Cdim * Cdim * 2);
    unsigned short* rqhi = (unsigned short*)alloc(GE * 2);
    unsigned short* rqlo = (unsigned short*)alloc(GE * 2);
    unsigned short* rghi = (unsigned short*)alloc(GE * 2);
    unsigned short* rglo = (unsigned short*)alloc(GE * 2);
    unsigned short* g2hi = (unsigned short*)alloc(GE * 2);
    unsigned short* g2lo = (unsigned short*)alloc(GE * 2);
    unsigned short* gThi = (unsigned short*)alloc(GE * 2);   // [NBLK][512][192]
    unsigned short* gTlo = (unsigned short*)alloc(GE * 2);
    unsigned short* sbhi = (unsigned short*)alloc((size_t)NBLK * BLK * BLK * 2);
    unsigned short* sblo = (unsigned short*)alloc((size_t)NBLK * BLK * BLK * 2);
    unsigned short* s2hi = (unsigned short*)alloc((size_t)CH * Ntok * Ntok * 2);
    unsigned short* s2lo = (unsigned short*)alloc((size_t)CH * Ntok * Ntok * 2);
    unsigned short* g2Thi = qhi;                             // [Bsz][512][1920]
    unsigned short* g2Tlo = qlo;

    // 1. token mean of g; per-row inv norms
    mean_partial<<<dim3(Bsz, 40), 512, 0, stream>>>(g, part);
    mean_final<<<Bsz, 512, 0, stream>>>(part, meang);
    invnorm_k<<<Mrows / 4, 256, 0, stream>>>(g, invn);

    // 2. hi/lo splits
    split_k<<<(int)(GE / 4 + 255) / 256, 256, 0, stream>>>(g, nullptr, ghi, glo, (int)(GE / 4));
    split_k<<<(int)(GE / 4 + 255) / 256, 256, 0, stream>>>(x, meang, qhi, qlo, (int)(GE / 4));
    split_k<<<(Cdim * Cdim / 4) / 256, 256, 0, stream>>>(Wq, nullptr, wqhi, wqlo, Cdim * Cdim / 4);
    split_k<<<(Cdim * Cdim / 4) / 256, 256, 0, stream>>>(Wg, nullptr, wghi, wglo, Cdim * Cdim / 4);

    // 2b. gT: per 192-block transpose of g  [NBLK][512][192]
    transpose2<<<dim3(Cdim / 64, BLK / 64, NBLK), 256, 0, stream>>>(
        ghi, glo, gThi, gTlo, BLK, Cdim, (long)BLK * Cdim, (long)Cdim * BLK);

    // 3. rel_q = q @ Wq^T -> split  [15360,512]   (q dead afterwards)
    mfma_gemm<<<dim3(Cdim / 128, Mrows / 128), 256, 0, stream>>>(
        qhi, qlo, wqhi, wqlo, nullptr, rqhi, rqlo,
        Mrows, Cdim, Cdim, 0, 0, 0, 1.0f, nullptr, nullptr, 0);

    // 4. block scores = (g·g^T)*invn_i*invn_j*SCALE -> split  [80][192][192]
    mfma_gemm<<<dim3(2, 2, NBLK), 256, 0, stream>>>(
        ghi, glo, ghi, glo, nullptr, sbhi, sblo,
        BLK, BLK, Cdim, (long)BLK * Cdim, (long)BLK * Cdim, (long)BLK * BLK,
        SCALE, invn, invn, BLK);

    // 5. block softmax in place
    softmax_inplace<<<NBLK * BLK, 256, 0, stream>>>(sbhi, sblo, BLK);

    // 6. g2 = attn @ gb = attn · (gT)^T -> split  [80][192][512]
    mfma_gemm<<<dim3(Cdim / 128, 2, NBLK), 256, 0, stream>>>(
        sbhi, sblo, gThi, gTlo, nullptr, g2hi, g2lo,
        BLK, Cdim, BLK, (long)BLK * BLK, (long)Cdim * BLK, (long)BLK * Cdim,
        1.0f, nullptr, nullptr, 0);

    // 6b. g2T: per-batch transpose of g2  [Bsz][512][1920]  (into dead q buffers)
    transpose2<<<dim3(Cdim / 64, Ntok / 64, Bsz), 256, 0, stream>>>(
        g2hi, g2lo, g2Thi, g2Tlo, Ntok, Cdim, (long)Ntok * Cdim, (long)Cdim * Ntok);

    // 7. rel_g = g2 @ Wg^T -> split  [15360,512]
    mfma_gemm<<<dim3(Cdim / 128, Mrows / 128), 256, 0, stream>>>(
        g2hi, g2lo, wghi, wglo, nullptr, rghi, rglo,
        Mrows, Cdim, Cdim, 0, 0, 0, 1.0f, nullptr, nullptr, 0);

    // 8. global attention, CH batches per chunk
    for (int c0 = 0; c0 < Bsz; c0 += CH) {
        size_t o2 = (size_t)c0 * Ntok * Cdim;
        // scores2 = rel_q @ rel_g^T * SCALE -> split  [CH][1920][1920]
        mfma_gemm<<<dim3(Ntok / 128, Ntok / 128, CH), 256, 0, stream>>>(
            rqhi + o2, rqlo + o2, rghi + o2, rglo + o2, nullptr, s2hi, s2lo,
            Ntok, Ntok, Cdim,
            (long)Ntok * Cdim, (long)Ntok * Cdim, (long)Ntok * Ntok,
            SCALE, nullptr, nullptr, 0);
        // softmax in place
        softmax_inplace<<<CH * Ntok, 256, 0, stream>>>(s2hi, s2lo, Ntok);
        // out = attn2 @ g2 = attn2 · (g2T)^T -> f32  [CH][1920][512]
        mfma_gemm<<<dim3(Cdim / 128, Ntok / 128, CH), 256, 0, stream>>>(
            s2hi, s2lo, g2Thi + (size_t)c0 * Cdim * Ntok, g2Tlo + (size_t)c0 * Cdim * Ntok,
            out + o2, nullptr, nullptr,
            Ntok, Cdim, Ntok,
            (long)Ntok * Ntok, (long)Cdim * Ntok, (long)Ntok * Cdim,
            1.0f, nullptr, nullptr, 0);
    }
}